// Round 11
// baseline (107.462 us; speedup 1.0000x reference)
//
#include <hip/hip_runtime.h>
#include <hip/hip_bf16.h>
#include <hip/hip_fp8.h>

// InfoNCE loss, N=8192 D=512 C=128.
// Fixed-shift softmax (M=10): t_ij = s_ij/tau - 10 in [-20, 0].
//   Z_i  = sum_{class!=} e^{t_ij}
//   term = -t_p + log(Z + e^{t_p}) ~= -t_p + logZ + e^{t_p}/Z
// r10 -> r11: occupancy was the limiter (25% = ~2 waves/SIMD; barrier+vmcnt
// stalls had nothing to hide behind). Same 128^2 fp8 tile, ring-3, counted
// vmcnt, conflict-free b128 swizzle -- but 8 waves/block (2x4 grid, 512 thr),
// per-wave 64x32 output, 2 gload_lds/wave/unit (vmcnt(2) steady). LDS still
// ~49 KB -> 3 blocks/CU = 24 waves/CU = 6/SIMD. No global stores inside the
// counted-vmcnt loop (r7 lesson). fp8 data layout: per 64B k-block, chunk c
// = k[c*8,+8) ++ k[32+c*8,+8) so one b128 read feeds both ks-operands.

constexpr int   D      = 512;
constexpr int   BT     = 128;
constexpr int   BK     = 64;         // bytes (fp8 elems) per unit
constexpr int   NSTEP  = D / BK;     // 8
constexpr float TAUINV = 10.0f;
constexpr float SHIFT  = 10.0f;

typedef __attribute__((ext_vector_type(4))) float f32x4;
typedef __attribute__((ext_vector_type(2))) long i64x2;
typedef unsigned char uchar;
typedef unsigned long ulong_t;

__device__ inline uchar f2fp8(float x) {
    __hip_fp8_e4m3 h(x);             // OCP e4m3fn, RNE+sat via HW cvt
    return (uchar)h.__x;
}

__device__ inline void gload_lds16(const uchar* g, void* l) {
    __builtin_amdgcn_global_load_lds(
        (const __attribute__((address_space(1))) void*)g,
        (__attribute__((address_space(3))) void*)l, 16, 0, 0);
}

// ---------------- K1: L2-normalize rows, f32 -> fp8 (+hist in block 0) ----
// Output layout: per 64B k-block, chunk c (16B) = k[c*8..+8) ++ k[32+c*8..+8).
__global__ void k_normalize(const float* __restrict__ emb,
                            const int* __restrict__ classes,
                            uchar* __restrict__ normed,
                            int* __restrict__ hist, int n) {
    if (blockIdx.x == 0) {
        __shared__ int h[128];
        if (threadIdx.x < 128) h[threadIdx.x] = 0;
        __syncthreads();
        for (int i = threadIdx.x; i < n; i += 256)
            atomicAdd(&h[classes[i] & 127], 1);
        __syncthreads();
        if (threadIdx.x < 128) hist[threadIdx.x] = h[threadIdx.x];
    }
    int row  = blockIdx.x * 4 + (threadIdx.x >> 6);
    int lane = threadIdx.x & 63;
    if (row >= n) return;
    const float4* src = (const float4*)(emb + (size_t)row * D);
    float4 a = src[lane * 2];
    float4 b = src[lane * 2 + 1];
    float ss = a.x*a.x + a.y*a.y + a.z*a.z + a.w*a.w
             + b.x*b.x + b.y*b.y + b.z*b.z + b.w*b.w;
#pragma unroll
    for (int m = 1; m < 64; m <<= 1) ss += __shfl_xor(ss, m, 64);
    float sc = 1.0f / fmaxf(sqrtf(ss), 1e-12f);
    union { uchar c[8]; ulong_t u; } o;
    o.c[0] = f2fp8(a.x * sc); o.c[1] = f2fp8(a.y * sc);
    o.c[2] = f2fp8(a.z * sc); o.c[3] = f2fp8(a.w * sc);
    o.c[4] = f2fp8(b.x * sc); o.c[5] = f2fp8(b.y * sc);
    o.c[6] = f2fp8(b.z * sc); o.c[7] = f2fp8(b.w * sc);
    int j8   = lane & 7;
    int doff = (lane >> 3) * 64 + (j8 & 3) * 16 + (j8 >> 2) * 8;
    *(ulong_t*)&normed[(size_t)row * D + doff] = o.u;
}

// ---------------- K2: symmetric masked-exp fp8 GEMM, 8 waves, ring-3 -------
// Zpart: plane q in 0..2 (Z,NS,P1), each [64 slots][n rows].
__global__ __launch_bounds__(512, 6) void k_zgemm(
    const uchar* __restrict__ normed, const int* __restrict__ classes,
    float* __restrict__ Zpart, int n, int nb, int npairs) {
    __shared__ char ring[3][16384];           // 3 units x (A 8KB | B 8KB)
    __shared__ int clsrow[BT], clscol[BT];

    const int tid  = threadIdx.x;
    const int lane = tid & 63;
    const int w    = tid >> 6;                // 0..7
    const int wm   = w >> 2, wn = w & 3;      // 2 x 4 wave grid
    const int l15  = lane & 15, l4 = lane >> 4;
    const size_t QS = (size_t)64 * n;

    // XCD-chunked bijective swizzle
    int q8 = npairs >> 3, r8 = npairs & 7;
    int xcd = blockIdx.x & 7, off = blockIdx.x >> 3;
    int orig = (xcd < r8 ? xcd * (q8 + 1) : r8 * (q8 + 1) + (xcd - r8) * q8) + off;

    // orig -> (bi,bj) via 8x8 supertile walk (2D locality within an XCD)
    const int sgrid = nb >> 3;               // 8
    int idx = orig, si = 0;
    for (;;) { int rc = 36 + (sgrid - 1 - si) * 64; if (idx < rc) break; idx -= rc; ++si; }
    int bi, bj;
    if (idx < 36) { int u = 0, rem = 8; while (idx >= rem) { idx -= rem; ++u; --rem; }
                    bi = si * 8 + u; bj = si * 8 + u + idx; }
    else { idx -= 36; int sj = si + 1 + (idx >> 6); int v = idx & 63;
           bi = si * 8 + (v >> 3); bj = sj * 8 + (v & 7); }
    const int row0 = bi * BT, c0 = bj * BT;
    const bool diagblk = (bi == bj);

    if (tid < BT) clsrow[tid] = classes[row0 + tid];
    else if (tid < 2 * BT) clscol[tid - BT] = classes[c0 + tid - BT];
    int crow[16];
#pragma unroll
    for (int t = 0; t < 16; ++t)
        crow[t] = classes[row0 + wm * 64 + (t >> 2) * 16 + l4 * 4 + (t & 3)];

    // staging: chunk = 16 rows x 64B (1KB); wave w owns chunk w of A and B.
    // lane l: row = w*16 + (l>>2); dst = base + lane*16 (linear).
    // source 16B slot pre-swizzled: src16 = (l&3) ^ ((l>>3)&3) (involution).
    const int src16 = (lane & 3) ^ ((lane >> 3) & 3);
    const size_t gA = (size_t)(row0 + w * 16 + (lane >> 2)) * D + src16 * 16;
    const size_t gB = (size_t)(c0   + w * 16 + (lane >> 2)) * D + src16 * 16;
    const int lo = w * 1024;
    char* ringb = &ring[0][0];

    auto STAGE = [&](int sbo, int kk) {       // kk = unit * 64 (bytes)
        gload_lds16(normed + gA + kk, ringb + sbo + lo);
        gload_lds16(normed + gB + kk, ringb + sbo + 8192 + lo);
    };

    f32x4 acc[4][2];
#pragma unroll
    for (int a = 0; a < 4; ++a)
#pragma unroll
        for (int b = 0; b < 2; ++b) acc[a][b] = (f32x4){0.f, 0.f, 0.f, 0.f};

    STAGE(0, 0);
    STAGE(16384, BK);
    __builtin_amdgcn_sched_barrier(0);
    asm volatile("s_waitcnt vmcnt(2) lgkmcnt(0)" ::: "memory");
    __builtin_amdgcn_s_barrier();
    __builtin_amdgcn_sched_barrier(0);

    // b128 read: 16B slot = l4 ^ ((l15>>1)&3)  (conflict-free, r10-measured)
    const int rsw = (l15 >> 1) & 3;

#pragma unroll
    for (int kt = 0; kt < NSTEP; ++kt) {
        const int cur = kt % 3;
        if (kt + 2 < NSTEP) STAGE(((kt + 2) % 3) * 16384, (kt + 2) * BK);
        const char* la = ringb + cur * 16384;
        const char* lb = la + 8192;
        i64x2 af[4], bfr[2];
#pragma unroll
        for (int mf = 0; mf < 4; ++mf) {
            int ra = wm * 64 + mf * 16 + l15;
            af[mf] = *(const i64x2*)(la + ra * 64 + ((l4 ^ rsw) << 4));
        }
#pragma unroll
        for (int nf = 0; nf < 2; ++nf) {
            int rb = wn * 32 + nf * 16 + l15;
            bfr[nf] = *(const i64x2*)(lb + rb * 64 + ((l4 ^ rsw) << 4));
        }
        __builtin_amdgcn_s_setprio(1);
#pragma unroll
        for (int mf = 0; mf < 4; ++mf)
#pragma unroll
            for (int nf = 0; nf < 2; ++nf) {
                acc[mf][nf] = __builtin_amdgcn_mfma_f32_16x16x32_fp8_fp8(
                    af[mf][0], bfr[nf][0], acc[mf][nf], 0, 0, 0);
                acc[mf][nf] = __builtin_amdgcn_mfma_f32_16x16x32_fp8_fp8(
                    af[mf][1], bfr[nf][1], acc[mf][nf], 0, 0, 0);
            }
        __builtin_amdgcn_s_setprio(0);
        __builtin_amdgcn_sched_barrier(0);
        if (kt + 2 < NSTEP)       asm volatile("s_waitcnt vmcnt(2)" ::: "memory");
        else if (kt + 2 == NSTEP) asm volatile("s_waitcnt vmcnt(0)" ::: "memory");
        if (kt + 1 < NSTEP) {
            __builtin_amdgcn_s_barrier();
            __builtin_amdgcn_sched_barrier(0);
        }
    }
    __syncthreads();   // full drain before LDS overlay

    // ---- epilogue: masked accumulation of (Z, NS, P1) ----
    float cqz[2] = {0,0}, cqn[2] = {0,0}, cqp[2] = {0,0};
    float* redr = (float*)ringb;              // [4(wn)][128][3] = 6 KB
    float* redc = (float*)(ringb + 8192);     // [2(wm)][128][3] = 3 KB

#pragma unroll
    for (int mf = 0; mf < 4; ++mf) {
#pragma unroll
        for (int r = 0; r < 4; ++r) {
            int rr = wm * 64 + mf * 16 + l4 * 4 + r;
            int rg = row0 + rr;
            int cr = crow[mf * 4 + r];
            float z = 0.f, ns = 0.f, p1 = 0.f;
#pragma unroll
            for (int nf = 0; nf < 2; ++nf) {
                int cc = wn * 32 + nf * 16 + l15;
                float t = fmaf(acc[mf][nf][r], TAUINV, -SHIFT);
                float e = __expf(t);
                bool same = (cr == clscol[cc]);
                bool dg   = (rg == c0 + cc);
                if (!same) { z += e; cqz[nf] += e; }
                else if (!dg) { ns += t; p1 += e; cqn[nf] += t; cqp[nf] += e; }
            }
#pragma unroll
            for (int m = 1; m < 16; m <<= 1) {
                z  += __shfl_xor(z,  m, 16);
                ns += __shfl_xor(ns, m, 16);
                p1 += __shfl_xor(p1, m, 16);
            }
            if (l15 == 0) {
                float* p = &redr[(wn * 128 + rr) * 3];
                p[0] = z; p[1] = ns; p[2] = p1;
            }
        }
    }
    if (!diagblk) {
#pragma unroll
        for (int nf = 0; nf < 2; ++nf) {
            float z = cqz[nf], nsv = cqn[nf], p = cqp[nf];
            z += __shfl_xor(z, 16, 64);  z += __shfl_xor(z, 32, 64);
            nsv += __shfl_xor(nsv, 16, 64); nsv += __shfl_xor(nsv, 32, 64);
            p += __shfl_xor(p, 16, 64);  p += __shfl_xor(p, 32, 64);
            if (l4 == 0) {
                int cc = wn * 32 + nf * 16 + l15;
                float* pp = &redc[(wm * 128 + cc) * 3];
                pp[0] = z; pp[1] = nsv; pp[2] = p;
            }
        }
    }
    __syncthreads();

    if (tid < BT) {                           // row-side partials, slot = bj
#pragma unroll
        for (int q = 0; q < 3; ++q)
            Zpart[q * QS + (size_t)bj * n + row0 + tid] =
                redr[(0 * 128 + tid) * 3 + q] + redr[(1 * 128 + tid) * 3 + q] +
                redr[(2 * 128 + tid) * 3 + q] + redr[(3 * 128 + tid) * 3 + q];
    } else if (tid < 2 * BT && !diagblk) {    // col-side partials, slot = bi
        int cc = tid - BT;
#pragma unroll
        for (int q = 0; q < 3; ++q)
            Zpart[q * QS + (size_t)bi * n + c0 + cc] =
                redc[(0 * 128 + cc) * 3 + q] + redc[(1 * 128 + cc) * 3 + q];
    }
}

// ---------------- K3: per-row closed-form terms ----------------
__global__ void k_rowterms(const float* __restrict__ Zpart,
                           const int* __restrict__ classes,
                           const int* __restrict__ hist,
                           float* __restrict__ rowloss,
                           float* __restrict__ rowcnt, int n) {
    int i = blockIdx.x * 256 + threadIdx.x;
    if (i >= n) return;
    const size_t QS = (size_t)64 * n;
    float z = 0.f, ns = 0.f, p1 = 0.f;
    for (int s = 0; s < 64; ++s) {
        size_t o = (size_t)s * n + i;
        z  += Zpart[o];
        ns += Zpart[QS + o];
        p1 += Zpart[2 * QS + o];
    }
    float c = (float)(hist[classes[i] & 127] - 1);
    rowloss[i] = -ns + c * logf(z) + p1 / z;
    rowcnt[i]  = c;
}

// ---------------- K4: final deterministic reduction ----------------
__global__ void k_final(const float* __restrict__ rowloss,
                        const float* __restrict__ rowcnt,
                        float* __restrict__ out, int n) {
    __shared__ float sl[1024];
    __shared__ float sc[1024];
    float l = 0.f, c = 0.f;
    for (int i = threadIdx.x; i < n; i += 1024) {
        l += rowloss[i];
        c += rowcnt[i];
    }
    sl[threadIdx.x] = l;
    sc[threadIdx.x] = c;
    __syncthreads();
    for (int s = 512; s > 0; s >>= 1) {
        if (threadIdx.x < s) {
            sl[threadIdx.x] += sl[threadIdx.x + s];
            sc[threadIdx.x] += sc[threadIdx.x + s];
        }
        __syncthreads();
    }
    if (threadIdx.x == 0)
        out[0] = (sc[0] > 0.f) ? sl[0] / sc[0] : 0.f;
}

extern "C" void kernel_launch(void* const* d_in, const int* in_sizes, int n_in,
                              void* d_out, int out_size, void* d_ws, size_t ws_size,
                              hipStream_t stream) {
    const float* emb     = (const float*)d_in[0];
    const int*   classes = (const int*)d_in[1];
    float*       out     = (float*)d_out;
    const int n  = in_sizes[1];               // 8192
    const int nb = n / BT;                    // 64
    const int npairs = nb * (nb + 1) / 2;     // 2080

    uchar*  normed  = (uchar*)d_ws;                                    // 4 MB
    float*  Zpart   = (float*)((char*)d_ws + (size_t)n * D);           // 6 MB
    float*  rowloss = Zpart + (size_t)3 * 64 * n;
    float*  rowcnt  = rowloss + n;
    int*    hist    = (int*)(rowcnt + n);                              // 512 B

    k_normalize<<<n / 4, 256, 0, stream>>>(emb, classes, normed, hist, n);
    k_zgemm<<<npairs, 512, 0, stream>>>(normed, classes, Zpart, n, nb, npairs);
    k_rowterms<<<(n + 255) / 256, 256, 0, stream>>>(Zpart, classes, hist, rowloss, rowcnt, n);
    k_final<<<1, 1024, 0, stream>>>(rowloss, rowcnt, out, n);
}

// Round 12
// 97.006 us; speedup vs baseline: 1.1078x; 1.1078x over previous
//
#include <hip/hip_runtime.h>
#include <hip/hip_bf16.h>
#include <hip/hip_fp8.h>

// InfoNCE loss, N=8192 D=512 C=128.
// Fixed-shift softmax (M=10): t_ij = s_ij/tau - 10 in [-20, 0].
//   Z_i  = sum_{class!=} e^{t_ij}
//   term = -t_p + log(Z + e^{t_p}) ~= -t_p + logZ + e^{t_p}/Z
// r11 -> r12: identical 8-wave fp8 kernel, but __launch_bounds__(512, 4).
// r11's (512,6) demanded 24 waves/CU => VGPR<=64 (m69 bands) => allocator
// spilled acc to scratch (VGPR 40, WRITE_SIZE 72MB) and tanked. (512,4)
// targets 16 waves/CU (VGPR<=128, kernel needs ~72) -> no spills, still
// +33% TLP over r10's 12 waves/CU. Everything else unchanged: ring-3,
// counted vmcnt(2), conflict-free b128 swizzle, interleaved fp8 layout,
// supertile + XCD walk, no global stores inside the counted-vmcnt loop.

constexpr int   D      = 512;
constexpr int   BT     = 128;
constexpr int   BK     = 64;         // bytes (fp8 elems) per unit
constexpr int   NSTEP  = D / BK;     // 8
constexpr float TAUINV = 10.0f;
constexpr float SHIFT  = 10.0f;

typedef __attribute__((ext_vector_type(4))) float f32x4;
typedef __attribute__((ext_vector_type(2))) long i64x2;
typedef unsigned char uchar;
typedef unsigned long ulong_t;

__device__ inline uchar f2fp8(float x) {
    __hip_fp8_e4m3 h(x);             // OCP e4m3fn, RNE+sat via HW cvt
    return (uchar)h.__x;
}

__device__ inline void gload_lds16(const uchar* g, void* l) {
    __builtin_amdgcn_global_load_lds(
        (const __attribute__((address_space(1))) void*)g,
        (__attribute__((address_space(3))) void*)l, 16, 0, 0);
}

// ---------------- K1: L2-normalize rows, f32 -> fp8 (+hist in block 0) ----
// Output layout: per 64B k-block, chunk c (16B) = k[c*8..+8) ++ k[32+c*8..+8).
__global__ void k_normalize(const float* __restrict__ emb,
                            const int* __restrict__ classes,
                            uchar* __restrict__ normed,
                            int* __restrict__ hist, int n) {
    if (blockIdx.x == 0) {
        __shared__ int h[128];
        if (threadIdx.x < 128) h[threadIdx.x] = 0;
        __syncthreads();
        for (int i = threadIdx.x; i < n; i += 256)
            atomicAdd(&h[classes[i] & 127], 1);
        __syncthreads();
        if (threadIdx.x < 128) hist[threadIdx.x] = h[threadIdx.x];
    }
    int row  = blockIdx.x * 4 + (threadIdx.x >> 6);
    int lane = threadIdx.x & 63;
    if (row >= n) return;
    const float4* src = (const float4*)(emb + (size_t)row * D);
    float4 a = src[lane * 2];
    float4 b = src[lane * 2 + 1];
    float ss = a.x*a.x + a.y*a.y + a.z*a.z + a.w*a.w
             + b.x*b.x + b.y*b.y + b.z*b.z + b.w*b.w;
#pragma unroll
    for (int m = 1; m < 64; m <<= 1) ss += __shfl_xor(ss, m, 64);
    float sc = 1.0f / fmaxf(sqrtf(ss), 1e-12f);
    union { uchar c[8]; ulong_t u; } o;
    o.c[0] = f2fp8(a.x * sc); o.c[1] = f2fp8(a.y * sc);
    o.c[2] = f2fp8(a.z * sc); o.c[3] = f2fp8(a.w * sc);
    o.c[4] = f2fp8(b.x * sc); o.c[5] = f2fp8(b.y * sc);
    o.c[6] = f2fp8(b.z * sc); o.c[7] = f2fp8(b.w * sc);
    int j8   = lane & 7;
    int doff = (lane >> 3) * 64 + (j8 & 3) * 16 + (j8 >> 2) * 8;
    *(ulong_t*)&normed[(size_t)row * D + doff] = o.u;
}

// ---------------- K2: symmetric masked-exp fp8 GEMM, 8 waves, ring-3 -------
// Zpart: plane q in 0..2 (Z,NS,P1), each [64 slots][n rows].
__global__ __launch_bounds__(512, 4) void k_zgemm(
    const uchar* __restrict__ normed, const int* __restrict__ classes,
    float* __restrict__ Zpart, int n, int nb, int npairs) {
    __shared__ char ring[3][16384];           // 3 units x (A 8KB | B 8KB)
    __shared__ int clsrow[BT], clscol[BT];

    const int tid  = threadIdx.x;
    const int lane = tid & 63;
    const int w    = tid >> 6;                // 0..7
    const int wm   = w >> 2, wn = w & 3;      // 2 x 4 wave grid
    const int l15  = lane & 15, l4 = lane >> 4;
    const size_t QS = (size_t)64 * n;

    // XCD-chunked bijective swizzle
    int q8 = npairs >> 3, r8 = npairs & 7;
    int xcd = blockIdx.x & 7, off = blockIdx.x >> 3;
    int orig = (xcd < r8 ? xcd * (q8 + 1) : r8 * (q8 + 1) + (xcd - r8) * q8) + off;

    // orig -> (bi,bj) via 8x8 supertile walk (2D locality within an XCD)
    const int sgrid = nb >> 3;               // 8
    int idx = orig, si = 0;
    for (;;) { int rc = 36 + (sgrid - 1 - si) * 64; if (idx < rc) break; idx -= rc; ++si; }
    int bi, bj;
    if (idx < 36) { int u = 0, rem = 8; while (idx >= rem) { idx -= rem; ++u; --rem; }
                    bi = si * 8 + u; bj = si * 8 + u + idx; }
    else { idx -= 36; int sj = si + 1 + (idx >> 6); int v = idx & 63;
           bi = si * 8 + (v >> 3); bj = sj * 8 + (v & 7); }
    const int row0 = bi * BT, c0 = bj * BT;
    const bool diagblk = (bi == bj);

    if (tid < BT) clsrow[tid] = classes[row0 + tid];
    else if (tid < 2 * BT) clscol[tid - BT] = classes[c0 + tid - BT];
    int crow[16];
#pragma unroll
    for (int t = 0; t < 16; ++t)
        crow[t] = classes[row0 + wm * 64 + (t >> 2) * 16 + l4 * 4 + (t & 3)];

    // staging: chunk = 16 rows x 64B (1KB); wave w owns chunk w of A and B.
    // lane l: row = w*16 + (l>>2); dst = base + lane*16 (linear).
    // source 16B slot pre-swizzled: src16 = (l&3) ^ ((l>>3)&3) (involution).
    const int src16 = (lane & 3) ^ ((lane >> 3) & 3);
    const size_t gA = (size_t)(row0 + w * 16 + (lane >> 2)) * D + src16 * 16;
    const size_t gB = (size_t)(c0   + w * 16 + (lane >> 2)) * D + src16 * 16;
    const int lo = w * 1024;
    char* ringb = &ring[0][0];

    auto STAGE = [&](int sbo, int kk) {       // kk = unit * 64 (bytes)
        gload_lds16(normed + gA + kk, ringb + sbo + lo);
        gload_lds16(normed + gB + kk, ringb + sbo + 8192 + lo);
    };

    f32x4 acc[4][2];
#pragma unroll
    for (int a = 0; a < 4; ++a)
#pragma unroll
        for (int b = 0; b < 2; ++b) acc[a][b] = (f32x4){0.f, 0.f, 0.f, 0.f};

    STAGE(0, 0);
    STAGE(16384, BK);
    __builtin_amdgcn_sched_barrier(0);
    asm volatile("s_waitcnt vmcnt(2) lgkmcnt(0)" ::: "memory");
    __builtin_amdgcn_s_barrier();
    __builtin_amdgcn_sched_barrier(0);

    // b128 read: 16B slot = l4 ^ ((l15>>1)&3)  (conflict-free, r10-measured)
    const int rsw = (l15 >> 1) & 3;

#pragma unroll
    for (int kt = 0; kt < NSTEP; ++kt) {
        const int cur = kt % 3;
        if (kt + 2 < NSTEP) STAGE(((kt + 2) % 3) * 16384, (kt + 2) * BK);
        const char* la = ringb + cur * 16384;
        const char* lb = la + 8192;
        i64x2 af[4], bfr[2];
#pragma unroll
        for (int mf = 0; mf < 4; ++mf) {
            int ra = wm * 64 + mf * 16 + l15;
            af[mf] = *(const i64x2*)(la + ra * 64 + ((l4 ^ rsw) << 4));
        }
#pragma unroll
        for (int nf = 0; nf < 2; ++nf) {
            int rb = wn * 32 + nf * 16 + l15;
            bfr[nf] = *(const i64x2*)(lb + rb * 64 + ((l4 ^ rsw) << 4));
        }
        __builtin_amdgcn_s_setprio(1);
#pragma unroll
        for (int mf = 0; mf < 4; ++mf)
#pragma unroll
            for (int nf = 0; nf < 2; ++nf) {
                acc[mf][nf] = __builtin_amdgcn_mfma_f32_16x16x32_fp8_fp8(
                    af[mf][0], bfr[nf][0], acc[mf][nf], 0, 0, 0);
                acc[mf][nf] = __builtin_amdgcn_mfma_f32_16x16x32_fp8_fp8(
                    af[mf][1], bfr[nf][1], acc[mf][nf], 0, 0, 0);
            }
        __builtin_amdgcn_s_setprio(0);
        __builtin_amdgcn_sched_barrier(0);
        if (kt + 2 < NSTEP)       asm volatile("s_waitcnt vmcnt(2)" ::: "memory");
        else if (kt + 2 == NSTEP) asm volatile("s_waitcnt vmcnt(0)" ::: "memory");
        if (kt + 1 < NSTEP) {
            __builtin_amdgcn_s_barrier();
            __builtin_amdgcn_sched_barrier(0);
        }
    }
    __syncthreads();   // full drain before LDS overlay

    // ---- epilogue: masked accumulation of (Z, NS, P1) ----
    float cqz[2] = {0,0}, cqn[2] = {0,0}, cqp[2] = {0,0};
    float* redr = (float*)ringb;              // [4(wn)][128][3] = 6 KB
    float* redc = (float*)(ringb + 8192);     // [2(wm)][128][3] = 3 KB

#pragma unroll
    for (int mf = 0; mf < 4; ++mf) {
#pragma unroll
        for (int r = 0; r < 4; ++r) {
            int rr = wm * 64 + mf * 16 + l4 * 4 + r;
            int rg = row0 + rr;
            int cr = crow[mf * 4 + r];
            float z = 0.f, ns = 0.f, p1 = 0.f;
#pragma unroll
            for (int nf = 0; nf < 2; ++nf) {
                int cc = wn * 32 + nf * 16 + l15;
                float t = fmaf(acc[mf][nf][r], TAUINV, -SHIFT);
                float e = __expf(t);
                bool same = (cr == clscol[cc]);
                bool dg   = (rg == c0 + cc);
                if (!same) { z += e; cqz[nf] += e; }
                else if (!dg) { ns += t; p1 += e; cqn[nf] += t; cqp[nf] += e; }
            }
#pragma unroll
            for (int m = 1; m < 16; m <<= 1) {
                z  += __shfl_xor(z,  m, 16);
                ns += __shfl_xor(ns, m, 16);
                p1 += __shfl_xor(p1, m, 16);
            }
            if (l15 == 0) {
                float* p = &redr[(wn * 128 + rr) * 3];
                p[0] = z; p[1] = ns; p[2] = p1;
            }
        }
    }
    if (!diagblk) {
#pragma unroll
        for (int nf = 0; nf < 2; ++nf) {
            float z = cqz[nf], nsv = cqn[nf], p = cqp[nf];
            z += __shfl_xor(z, 16, 64);  z += __shfl_xor(z, 32, 64);
            nsv += __shfl_xor(nsv, 16, 64); nsv += __shfl_xor(nsv, 32, 64);
            p += __shfl_xor(p, 16, 64);  p += __shfl_xor(p, 32, 64);
            if (l4 == 0) {
                int cc = wn * 32 + nf * 16 + l15;
                float* pp = &redc[(wm * 128 + cc) * 3];
                pp[0] = z; pp[1] = nsv; pp[2] = p;
            }
        }
    }
    __syncthreads();

    if (tid < BT) {                           // row-side partials, slot = bj
#pragma unroll
        for (int q = 0; q < 3; ++q)
            Zpart[q * QS + (size_t)bj * n + row0 + tid] =
                redr[(0 * 128 + tid) * 3 + q] + redr[(1 * 128 + tid) * 3 + q] +
                redr[(2 * 128 + tid) * 3 + q] + redr[(3 * 128 + tid) * 3 + q];
    } else if (tid < 2 * BT && !diagblk) {    // col-side partials, slot = bi
        int cc = tid - BT;
#pragma unroll
        for (int q = 0; q < 3; ++q)
            Zpart[q * QS + (size_t)bi * n + c0 + cc] =
                redc[(0 * 128 + cc) * 3 + q] + redc[(1 * 128 + cc) * 3 + q];
    }
}

// ---------------- K3: per-row closed-form terms ----------------
__global__ void k_rowterms(const float* __restrict__ Zpart,
                           const int* __restrict__ classes,
                           const int* __restrict__ hist,
                           float* __restrict__ rowloss,
                           float* __restrict__ rowcnt, int n) {
    int i = blockIdx.x * 256 + threadIdx.x;
    if (i >= n) return;
    const size_t QS = (size_t)64 * n;
    float z = 0.f, ns = 0.f, p1 = 0.f;
    for (int s = 0; s < 64; ++s) {
        size_t o = (size_t)s * n + i;
        z  += Zpart[o];
        ns += Zpart[QS + o];
        p1 += Zpart[2 * QS + o];
    }
    float c = (float)(hist[classes[i] & 127] - 1);
    rowloss[i] = -ns + c * logf(z) + p1 / z;
    rowcnt[i]  = c;
}

// ---------------- K4: final deterministic reduction ----------------
__global__ void k_final(const float* __restrict__ rowloss,
                        const float* __restrict__ rowcnt,
                        float* __restrict__ out, int n) {
    __shared__ float sl[1024];
    __shared__ float sc[1024];
    float l = 0.f, c = 0.f;
    for (int i = threadIdx.x; i < n; i += 1024) {
        l += rowloss[i];
        c += rowcnt[i];
    }
    sl[threadIdx.x] = l;
    sc[threadIdx.x] = c;
    __syncthreads();
    for (int s = 512; s > 0; s >>= 1) {
        if (threadIdx.x < s) {
            sl[threadIdx.x] += sl[threadIdx.x + s];
            sc[threadIdx.x] += sc[threadIdx.x + s];
        }
        __syncthreads();
    }
    if (threadIdx.x == 0)
        out[0] = (sc[0] > 0.f) ? sl[0] / sc[0] : 0.f;
}

extern "C" void kernel_launch(void* const* d_in, const int* in_sizes, int n_in,
                              void* d_out, int out_size, void* d_ws, size_t ws_size,
                              hipStream_t stream) {
    const float* emb     = (const float*)d_in[0];
    const int*   classes = (const int*)d_in[1];
    float*       out     = (float*)d_out;
    const int n  = in_sizes[1];               // 8192
    const int nb = n / BT;                    // 64
    const int npairs = nb * (nb + 1) / 2;     // 2080

    uchar*  normed  = (uchar*)d_ws;                                    // 4 MB
    float*  Zpart   = (float*)((char*)d_ws + (size_t)n * D);           // 6 MB
    float*  rowloss = Zpart + (size_t)3 * 64 * n;
    float*  rowcnt  = rowloss + n;
    int*    hist    = (int*)(rowcnt + n);                              // 512 B

    k_normalize<<<n / 4, 256, 0, stream>>>(emb, classes, normed, hist, n);
    k_zgemm<<<npairs, 512, 0, stream>>>(normed, classes, Zpart, n, nb, npairs);
    k_rowterms<<<(n + 255) / 256, 256, 0, stream>>>(Zpart, classes, hist, rowloss, rowcnt, n);
    k_final<<<1, 1024, 0, stream>>>(rowloss, rowcnt, out, n);
}